// Round 3
// baseline (104.710 us; speedup 1.0000x reference)
//
#include <hip/hip_runtime.h>

// Problem constants (from reference setup_inputs)
constexpr int B = 8, C = 3, H = 544, W = 960;
constexpr int KH = 3, KW = 3;
constexpr int HW = H * W;        // 522240
constexpr int WT = 8;            // outputs per thread along W
constexpr int WQ = W / WT;       // 120
constexpr int NK = C * KH * KW;  // 27 filter planes
constexpr int BLOCK = 256;
constexpr int TOTAL = B * H * WQ;    // 522240 threads
constexpr int NBLK = TOTAL / BLOCK;  // 2040 blocks
static_assert(TOTAL % BLOCK == 0, "grid must be exact");
static_assert(NBLK % 8 == 0, "swizzle must be bijective");

typedef float f32x4 __attribute__((ext_vector_type(4)));

__global__ __launch_bounds__(BLOCK) void DynFilter_kernel(
    const float* __restrict__ x,     // [B, C, H, W]
    const float* __restrict__ filt,  // [B, 27, H, W]
    float* __restrict__ out)         // [B, 1, H, W]
{
    // XCD-aware chunked swizzle (neutral but harmless; keeps x locality per XCD)
    int bid  = (int)blockIdx.x;
    int sbid = (bid & 7) * (NBLK / 8) + (bid >> 3);
    int tid  = sbid * BLOCK + (int)threadIdx.x;

    int wq = tid % WQ;
    int t  = tid / WQ;
    int h  = t % H;
    int b  = t / H;
    int w0 = wq * WT;

    f32x4 acc0 = {0.f, 0.f, 0.f, 0.f};
    f32x4 acc1 = {0.f, 0.f, 0.f, 0.f};

    const float* fbase = filt + (size_t)b * NK * HW + (size_t)h * W + w0;

    #pragma unroll
    for (int c = 0; c < C; ++c) {
        const float* xc = x + ((size_t)b * C + c) * HW;
        #pragma unroll
        for (int i = 0; i < KH; ++i) {
            int hr = h + i - 1;
            bool vh = (unsigned)hr < (unsigned)H;
            // xv[q] holds x column (w0 - 1 + q), q = 0..9 — cached loads (x is hot)
            float xv[WT + 2];
            if (vh) {
                const float* xr = xc + (size_t)hr * W + w0;  // 16B aligned
                f32x4 m0 = *reinterpret_cast<const f32x4*>(xr);
                f32x4 m1 = *reinterpret_cast<const f32x4*>(xr + 4);
                xv[1] = m0[0]; xv[2] = m0[1]; xv[3] = m0[2]; xv[4] = m0[3];
                xv[5] = m1[0]; xv[6] = m1[1]; xv[7] = m1[2]; xv[8] = m1[3];
                xv[0] = (w0 > 0)      ? xr[-1] : 0.f;
                xv[9] = (w0 + WT < W) ? xr[WT] : 0.f;
            } else {
                #pragma unroll
                for (int q = 0; q < WT + 2; ++q) xv[q] = 0.f;
            }
            #pragma unroll
            for (int j = 0; j < KW; ++j) {
                int k = c * (KH * KW) + i * KW + j;
                const float* fp = fbase + (size_t)k * HW;
                // filter: 451 MB streamed exactly once -> non-temporal (don't
                // evict the 50 MB, 27x-reused x from L2/L3)
                f32x4 f0 = __builtin_nontemporal_load(reinterpret_cast<const f32x4*>(fp));
                f32x4 f1 = __builtin_nontemporal_load(reinterpret_cast<const f32x4*>(fp) + 1);
                acc0[0] += xv[j]     * f0[0];
                acc0[1] += xv[j + 1] * f0[1];
                acc0[2] += xv[j + 2] * f0[2];
                acc0[3] += xv[j + 3] * f0[3];
                acc1[0] += xv[j + 4] * f1[0];
                acc1[1] += xv[j + 5] * f1[1];
                acc1[2] += xv[j + 6] * f1[2];
                acc1[3] += xv[j + 7] * f1[3];
            }
        }
    }

    float* op = out + (size_t)b * HW + (size_t)h * W + w0;
    __builtin_nontemporal_store(acc0, reinterpret_cast<f32x4*>(op));
    __builtin_nontemporal_store(acc1, reinterpret_cast<f32x4*>(op) + 1);
}

extern "C" void kernel_launch(void* const* d_in, const int* in_sizes, int n_in,
                              void* d_out, int out_size, void* d_ws, size_t ws_size,
                              hipStream_t stream) {
    const float* x    = (const float*)d_in[0];
    const float* filt = (const float*)d_in[1];
    float* out        = (float*)d_out;

    DynFilter_kernel<<<NBLK, BLOCK, 0, stream>>>(x, filt, out);
}

// Round 4
// 92.709 us; speedup vs baseline: 1.1294x; 1.1294x over previous
//
#include <hip/hip_runtime.h>

// Problem constants (from reference setup_inputs)
constexpr int B = 8, C = 3, H = 544, W = 960;
constexpr int KH = 3, KW = 3;
constexpr int HW = H * W;        // 522240
constexpr int WT = 8;            // outputs per thread along W
constexpr int HT = 2;            // output rows per thread
constexpr int WQ = W / WT;       // 120
constexpr int HG = H / HT;       // 272
constexpr int NK = C * KH * KW;  // 27 filter planes
constexpr int BLOCK = 256;
constexpr int TOTAL = B * HG * WQ;   // 261120 threads
constexpr int NBLK = TOTAL / BLOCK;  // 1020 blocks
static_assert(TOTAL % BLOCK == 0, "grid must be exact");

typedef float f32x4 __attribute__((ext_vector_type(4)));

__device__ __forceinline__ void load_row(const float* xr, bool valid,
                                         bool left, bool right,
                                         float xv[WT + 2]) {
    if (valid) {
        f32x4 m0 = *reinterpret_cast<const f32x4*>(xr);
        f32x4 m1 = *reinterpret_cast<const f32x4*>(xr + 4);
        xv[1] = m0[0]; xv[2] = m0[1]; xv[3] = m0[2]; xv[4] = m0[3];
        xv[5] = m1[0]; xv[6] = m1[1]; xv[7] = m1[2]; xv[8] = m1[3];
        xv[0] = left  ? xr[-1] : 0.f;
        xv[9] = right ? xr[WT] : 0.f;
    } else {
        #pragma unroll
        for (int q = 0; q < WT + 2; ++q) xv[q] = 0.f;
    }
}

__global__ __launch_bounds__(BLOCK) void DynFilter_kernel(
    const float* __restrict__ x,     // [B, C, H, W]
    const float* __restrict__ filt,  // [B, 27, H, W]
    float* __restrict__ out)         // [B, 1, H, W]
{
    int tid = (int)blockIdx.x * BLOCK + (int)threadIdx.x;

    int wq = tid % WQ;
    int t  = tid / WQ;
    int hg = t % HG;
    int b  = t / HG;
    int h0 = hg * HT;          // rows h0, h0+1 computed by this thread
    int w0 = wq * WT;
    bool left  = (w0 > 0);
    bool right = (w0 + WT < W);

    f32x4 a00 = {0,0,0,0}, a01 = {0,0,0,0};  // row h0, cols w0..w0+7
    f32x4 a10 = {0,0,0,0}, a11 = {0,0,0,0};  // row h0+1

    // filter base at row h0; row h0+1 reached via +W (3840 B immediate)
    const float* fbase = filt + (size_t)b * NK * HW + (size_t)h0 * W + w0;

    #pragma unroll
    for (int c = 0; c < C; ++c) {
        const float* xc = x + ((size_t)b * C + c) * HW;

        // rolling 4-row x window: rows h0-1 .. h0+2, each 10 cols
        float xva[WT + 2], xvb[WT + 2], xvc[WT + 2], xvd[WT + 2];
        load_row(xc + (size_t)(h0 - 1) * W + w0, h0 > 0,     left, right, xva);
        load_row(xc + (size_t)(h0    ) * W + w0, true,       left, right, xvb);
        load_row(xc + (size_t)(h0 + 1) * W + w0, true,       left, right, xvc);  // h0+1 <= H-1 always
        load_row(xc + (size_t)(h0 + 2) * W + w0, h0 + 2 < H, left, right, xvd);

        #pragma unroll
        for (int i = 0; i < KH; ++i) {
            // static selection of window rows (fully unrolled -> register-resident)
            const float* r0 = (i == 0) ? xva : (i == 1) ? xvb : xvc;  // for output row h0
            const float* r1 = (i == 0) ? xvb : (i == 1) ? xvc : xvd;  // for output row h0+1
            #pragma unroll
            for (int j = 0; j < KW; ++j) {
                int k = c * (KH * KW) + i * KW + j;
                const float* fp = fbase + (size_t)k * HW;
                f32x4 g0 = *reinterpret_cast<const f32x4*>(fp);          // row h0
                f32x4 g1 = *reinterpret_cast<const f32x4*>(fp + 4);
                f32x4 g2 = *reinterpret_cast<const f32x4*>(fp + W);      // row h0+1
                f32x4 g3 = *reinterpret_cast<const f32x4*>(fp + W + 4);
                #pragma unroll
                for (int q = 0; q < 4; ++q) {
                    a00[q] += r0[j + q]     * g0[q];
                    a01[q] += r0[j + q + 4] * g1[q];
                    a10[q] += r1[j + q]     * g2[q];
                    a11[q] += r1[j + q + 4] * g3[q];
                }
            }
        }
    }

    float* op = out + (size_t)b * HW + (size_t)h0 * W + w0;
    __builtin_nontemporal_store(a00, reinterpret_cast<f32x4*>(op));
    __builtin_nontemporal_store(a01, reinterpret_cast<f32x4*>(op) + 1);
    __builtin_nontemporal_store(a10, reinterpret_cast<f32x4*>(op + W));
    __builtin_nontemporal_store(a11, reinterpret_cast<f32x4*>(op + W) + 1);
}

extern "C" void kernel_launch(void* const* d_in, const int* in_sizes, int n_in,
                              void* d_out, int out_size, void* d_ws, size_t ws_size,
                              hipStream_t stream) {
    const float* x    = (const float*)d_in[0];
    const float* filt = (const float*)d_in[1];
    float* out        = (float*)d_out;

    DynFilter_kernel<<<NBLK, BLOCK, 0, stream>>>(x, filt, out);
}